// Round 15
// baseline (87.739 us; speedup 1.0000x reference)
//
#include <hip/hip_runtime.h>
#include <math.h>

#define NN 4096
#define MM 8
#define BLOCK 256
#define CC 128                 // j-chunks (grid.y)
#define JT 32                  // j-tile size = NN/CC
#define FOUR_PI_F 12.566370614359172f
#define EPS_F 1e-8f
#define LOG2E_F 1.4426950408889634f

// out[i][m] = sum_j exp(-d_ij/lam_m)/(4*pi*D_m*d_ij) * secretion[j][m]*active[j]
// d_ij = max(sqrt(|p_i-p_j|^2+eps), r_j)
//
// R15 occupancy experiment: C 64->128 (JT 64->32) doubles grid to 2048 blocks
// = 8 blocks/CU = 8 waves/SIMD (R7 measured VALUBusy 15.7% at low occupancy
// -> latency-bound hypothesis). Costs +8MB partial traffic. Reduce: same
// 512-block 16x16 tree, now 8 independent loads/thread.
// Math (unchanged from R12): squared-domain clamp (one rsqrt); exp2(d*na);
// ballot-prefix active-compaction (order-preserving); runtime-gated
// specializations: VAR1 shares one exp2 across bit-equal lam (m 0,1,5);
// VAR2 adds the lam 20:10:5 chain (e3=e2^2, e4=e3^2): 4 exp2 + 1 rsq/pair.

template <int VAR>
__device__ __forceinline__ void run_tile(
    int nact, const float4* __restrict__ sj, const float4* __restrict__ ss,
    float px, float py, float pz, const float* __restrict__ na,
    float* __restrict__ acc)
{
#pragma unroll 2
    for (int jj = 0; jj < nact; ++jj) {
        const float4 pj = sj[jj];
        const float4 s0 = ss[jj * 2 + 0];
        const float4 s1 = ss[jj * 2 + 1];
        float dx = px - pj.x;
        float dy = py - pj.y;
        float dz = pz - pj.z;
        float d2 = fmaf(dx, dx, fmaf(dy, dy, fmaf(dz, dz, EPS_F)));
        float d2c = fmaxf(d2, pj.w);            // clamp in squared domain
        float rs = __builtin_amdgcn_rsqf(d2c);  // 1/dist
        float dcl = d2c * rs;                   // dist

        if constexpr (VAR == 2) {
            float a0 = dcl * na[0], a2 = dcl * na[2];
            float a6 = dcl * na[6], a7 = dcl * na[7];
            float eA = __builtin_amdgcn_exp2f(a0);
            float e2 = __builtin_amdgcn_exp2f(a2);
            float e6 = __builtin_amdgcn_exp2f(a6);
            float e7 = __builtin_amdgcn_exp2f(a7);
            float e3 = e2 * e2;   // lam3 = lam2/2
            float e4 = e3 * e3;   // lam4 = lam3/2
            float fA = eA * rs, f2 = e2 * rs;
            float f3 = e3 * rs, f4 = e4 * rs;
            float f6 = e6 * rs, f7 = e7 * rs;
            acc[0] = fmaf(fA, s0.x, acc[0]);
            acc[1] = fmaf(fA, s0.y, acc[1]);
            acc[2] = fmaf(f2, s0.z, acc[2]);
            acc[3] = fmaf(f3, s0.w, acc[3]);
            acc[4] = fmaf(f4, s1.x, acc[4]);
            acc[5] = fmaf(fA, s1.y, acc[5]);
            acc[6] = fmaf(f6, s1.z, acc[6]);
            acc[7] = fmaf(f7, s1.w, acc[7]);
        } else if constexpr (VAR == 1) {
            float fA = __builtin_amdgcn_exp2f(dcl * na[0]) * rs;
            float f2 = __builtin_amdgcn_exp2f(dcl * na[2]) * rs;
            float f3 = __builtin_amdgcn_exp2f(dcl * na[3]) * rs;
            float f4 = __builtin_amdgcn_exp2f(dcl * na[4]) * rs;
            float f6 = __builtin_amdgcn_exp2f(dcl * na[6]) * rs;
            float f7 = __builtin_amdgcn_exp2f(dcl * na[7]) * rs;
            acc[0] = fmaf(fA, s0.x, acc[0]);
            acc[1] = fmaf(fA, s0.y, acc[1]);
            acc[2] = fmaf(f2, s0.z, acc[2]);
            acc[3] = fmaf(f3, s0.w, acc[3]);
            acc[4] = fmaf(f4, s1.x, acc[4]);
            acc[5] = fmaf(fA, s1.y, acc[5]);
            acc[6] = fmaf(f6, s1.z, acc[6]);
            acc[7] = fmaf(f7, s1.w, acc[7]);
        } else {
            const float s[MM] = {s0.x, s0.y, s0.z, s0.w,
                                 s1.x, s1.y, s1.z, s1.w};
#pragma unroll
            for (int m = 0; m < MM; ++m)
                acc[m] = fmaf(__builtin_amdgcn_exp2f(dcl * na[m]) * rs,
                              s[m], acc[m]);
        }
    }
}

// grid = (NN/BLOCK, C). Block: 256 i-rows x ntiles JT-wide j-tiles (compacted).
__global__ __launch_bounds__(BLOCK) void diff_partial(
    const float* __restrict__ pos, const float* __restrict__ radius,
    const float* __restrict__ secretion, const float* __restrict__ Dc,
    const float* __restrict__ Kd, const int* __restrict__ active,
    float* __restrict__ partial,   // C x NN x MM
    int ntiles)                    // tiles per chunk (1 when C=128)
{
    __shared__ float4 sj[JT];      // {x,y,z,r^2} of k-th ACTIVE j
    __shared__ float4 ss[JT * 2];  // premult secretion/(4*pi*D_m)
    __shared__ int s_nact;

    const int tid = threadIdx.x;
    const int i = blockIdx.x * BLOCK + tid;
    const int j0base = blockIdx.y * (JT * ntiles);

    float na[MM], invD[MM], acc[MM];
#pragma unroll
    for (int m = 0; m < MM; ++m) {
        float lam = sqrtf(Dc[m] / Kd[m]);   // exact div+sqrt: keeps the
        na[m] = -LOG2E_F / lam;             // dup015/chain bit-equality gates
        invD[m] = 1.0f / (FOUR_PI_F * Dc[m]);
        acc[m] = 0.0f;
    }
    const bool dup015 = (na[0] == na[1]) && (na[0] == na[5]);
    const bool chain =
        dup015 &&
        (fabsf(na[3] - 2.0f * na[2]) <= 4e-6f * fabsf(na[3])) &&
        (fabsf(na[4] - 2.0f * na[3]) <= 4e-6f * fabsf(na[4]));

    const float px = pos[i * 3 + 0];
    const float py = pos[i * 3 + 1];
    const float pz = pos[i * 3 + 2];

    for (int t = 0; t < ntiles; ++t) {
        const int j0 = j0base + t * JT;
        if (t) __syncthreads();  // protect LDS from previous tile's readers

        // Wave 0, lanes 0..JT-1 stage + compact (inactive lanes give 0 bits
        // in the ballot; prefix-popcount over (1<<tid)-1 stays correct).
        if (tid < JT) {
            const int j = j0 + tid;
            const bool act = (active[j] != 0);
            const unsigned long long mask = __ballot(act);
            if (tid == 0) s_nact = __popcll(mask);
            if (act) {
                const int k = __popcll(mask & ((1ull << tid) - 1ull));
                const float r = radius[j];
                sj[k] = make_float4(pos[j * 3 + 0], pos[j * 3 + 1],
                                    pos[j * 3 + 2], r * r);
                const float4 s0 =
                    reinterpret_cast<const float4*>(secretion)[j * 2 + 0];
                const float4 s1 =
                    reinterpret_cast<const float4*>(secretion)[j * 2 + 1];
                ss[k * 2 + 0] = make_float4(s0.x * invD[0], s0.y * invD[1],
                                            s0.z * invD[2], s0.w * invD[3]);
                ss[k * 2 + 1] = make_float4(s1.x * invD[4], s1.y * invD[5],
                                            s1.z * invD[6], s1.w * invD[7]);
            }
        }
        __syncthreads();

        const int nact = s_nact;
        if (chain)       run_tile<2>(nact, sj, ss, px, py, pz, na, acc);
        else if (dup015) run_tile<1>(nact, sj, ss, px, py, pz, na, acc);
        else             run_tile<0>(nact, sj, ss, px, py, pz, na, acc);
    }

    float4* dst = reinterpret_cast<float4*>(
        partial + (size_t)blockIdx.y * NN * MM + (size_t)i * MM);
    dst[0] = make_float4(acc[0], acc[1], acc[2], acc[3]);
    dst[1] = make_float4(acc[4], acc[5], acc[6], acc[7]);
}

// Reduce: 512 blocks. tx = 16 outputs/block, ty = 16 parallel c-slices
// (C/16 = 8 independent float4 loads per thread at C=128).
__global__ __launch_bounds__(BLOCK) void diff_reduce(
    const float4* __restrict__ partial, float4* __restrict__ out, int C)
{
    __shared__ float4 red[16][16];
    const int tx = threadIdx.x & 15;
    const int ty = threadIdx.x >> 4;
    const int o = blockIdx.x * 16 + tx;  // 0 .. NN*MM/4-1

    float4 s = make_float4(0.f, 0.f, 0.f, 0.f);
    for (int c = ty; c < C; c += 16) {
        const float4 p = partial[(size_t)c * (NN * MM / 4) + o];
        s.x += p.x; s.y += p.y; s.z += p.z; s.w += p.w;
    }
    red[ty][tx] = s;
    __syncthreads();
#pragma unroll
    for (int h = 8; h >= 1; h >>= 1) {
        if (ty < h) {
            float4 a = red[ty + h][tx];
            red[ty][tx].x += a.x; red[ty][tx].y += a.y;
            red[ty][tx].z += a.z; red[ty][tx].w += a.w;
        }
        __syncthreads();
    }
    if (ty == 0) out[o] = red[0][tx];
}

extern "C" void kernel_launch(void* const* d_in, const int* in_sizes, int n_in,
                              void* d_out, int out_size, void* d_ws, size_t ws_size,
                              hipStream_t stream) {
    const float* pos       = (const float*)d_in[0];
    const float* radius    = (const float*)d_in[1];
    const float* secretion = (const float*)d_in[2];
    const float* Dc        = (const float*)d_in[3];
    const float* Kd        = (const float*)d_in[4];
    const int*   active    = (const int*)d_in[5];
    float* out = (float*)d_out;

    const size_t slice = (size_t)NN * MM * sizeof(float);  // 128 KB

    int C = CC;
    while (C > 4 && (size_t)C * slice > ws_size) C >>= 1;
    const int ntiles = NN / (C * JT);  // 1 at C=128

    float* partial = (float*)d_ws;
    dim3 grid(NN / BLOCK, C);
    diff_partial<<<grid, BLOCK, 0, stream>>>(pos, radius, secretion, Dc, Kd,
                                             active, partial, ntiles);
    diff_reduce<<<(NN * MM / 4) / 16, BLOCK, 0, stream>>>(
        (const float4*)partial, (float4*)out, C);
}

// Round 16
// 79.020 us; speedup vs baseline: 1.1103x; 1.1103x over previous
//
#include <hip/hip_runtime.h>
#include <math.h>

#define NN 4096
#define MM 8
#define BLOCK 256
#define CC 64                  // j-chunks (grid.y)
#define JT 64                  // j-tile size
#define FOUR_PI_F 12.566370614359172f
#define EPS_F 1e-8f
#define LOG2E_F 1.4426950408889634f

// out[i][m] = sum_j exp(-d_ij/lam_m)/(4*pi*D_m*d_ij) * secretion[j][m]*active[j]
// d_ij = max(sqrt(|p_i-p_j|^2+eps), r_j)
//
// R16 = revert to R12/R14 exactly (measured 79.9 us; best). R15's C=128
// occupancy experiment regressed (87.7): partial is pipe-bound at C=64,
// and extra partial traffic + staging overhead dominate. C ladder measured:
// 32 (R7) worse / 64 best / 128 (R15) worse.
// Structure: partial (16,64)=1024 blocks, 4 waves/SIMD, active-compacted
// 64-j LDS tiles; reduce 512 blocks, 16 outputs x 16 c-slices + LDS tree.
// Math: squared-domain clamp (one rsqrt); exp2(d*na); ballot-prefix
// compaction (order-preserving); runtime-gated specializations:
// VAR1 shares one exp2 across bit-equal lam (m 0,1,5); VAR2 adds the
// lam 20:10:5 chain (e3=e2^2, e4=e3^2): 4 exp2 + 1 rsq per pair.

template <int VAR>
__device__ __forceinline__ void run_tile(
    int nact, const float4* __restrict__ sj, const float4* __restrict__ ss,
    float px, float py, float pz, const float* __restrict__ na,
    float* __restrict__ acc)
{
#pragma unroll 2
    for (int jj = 0; jj < nact; ++jj) {
        const float4 pj = sj[jj];
        const float4 s0 = ss[jj * 2 + 0];
        const float4 s1 = ss[jj * 2 + 1];
        float dx = px - pj.x;
        float dy = py - pj.y;
        float dz = pz - pj.z;
        float d2 = fmaf(dx, dx, fmaf(dy, dy, fmaf(dz, dz, EPS_F)));
        float d2c = fmaxf(d2, pj.w);            // clamp in squared domain
        float rs = __builtin_amdgcn_rsqf(d2c);  // 1/dist
        float dcl = d2c * rs;                   // dist

        if constexpr (VAR == 2) {
            // exp args paired: (na0,na2)*dcl, (na6,na7)*dcl
            float a0 = dcl * na[0], a2 = dcl * na[2];
            float a6 = dcl * na[6], a7 = dcl * na[7];
            float eA = __builtin_amdgcn_exp2f(a0);
            float e2 = __builtin_amdgcn_exp2f(a2);
            float e6 = __builtin_amdgcn_exp2f(a6);
            float e7 = __builtin_amdgcn_exp2f(a7);
            float e3 = e2 * e2;   // lam3 = lam2/2
            float e4 = e3 * e3;   // lam4 = lam3/2
            // rs-muls paired: (eA,e2), (e3,e4), (e6,e7)
            float fA = eA * rs, f2 = e2 * rs;
            float f3 = e3 * rs, f4 = e4 * rs;
            float f6 = e6 * rs, f7 = e7 * rs;
            // accumulate as 4 float2 pairs: (0,1)(2,3)(4,5)(6,7)
            acc[0] = fmaf(fA, s0.x, acc[0]);
            acc[1] = fmaf(fA, s0.y, acc[1]);
            acc[2] = fmaf(f2, s0.z, acc[2]);
            acc[3] = fmaf(f3, s0.w, acc[3]);
            acc[4] = fmaf(f4, s1.x, acc[4]);
            acc[5] = fmaf(fA, s1.y, acc[5]);
            acc[6] = fmaf(f6, s1.z, acc[6]);
            acc[7] = fmaf(f7, s1.w, acc[7]);
        } else if constexpr (VAR == 1) {
            float fA = __builtin_amdgcn_exp2f(dcl * na[0]) * rs;
            float f2 = __builtin_amdgcn_exp2f(dcl * na[2]) * rs;
            float f3 = __builtin_amdgcn_exp2f(dcl * na[3]) * rs;
            float f4 = __builtin_amdgcn_exp2f(dcl * na[4]) * rs;
            float f6 = __builtin_amdgcn_exp2f(dcl * na[6]) * rs;
            float f7 = __builtin_amdgcn_exp2f(dcl * na[7]) * rs;
            acc[0] = fmaf(fA, s0.x, acc[0]);
            acc[1] = fmaf(fA, s0.y, acc[1]);
            acc[2] = fmaf(f2, s0.z, acc[2]);
            acc[3] = fmaf(f3, s0.w, acc[3]);
            acc[4] = fmaf(f4, s1.x, acc[4]);
            acc[5] = fmaf(fA, s1.y, acc[5]);
            acc[6] = fmaf(f6, s1.z, acc[6]);
            acc[7] = fmaf(f7, s1.w, acc[7]);
        } else {
            const float s[MM] = {s0.x, s0.y, s0.z, s0.w,
                                 s1.x, s1.y, s1.z, s1.w};
#pragma unroll
            for (int m = 0; m < MM; ++m)
                acc[m] = fmaf(__builtin_amdgcn_exp2f(dcl * na[m]) * rs,
                              s[m], acc[m]);
        }
    }
}

// grid = (NN/BLOCK, C). Block: 256 i-rows x ntiles 64-wide j-tiles (compacted).
__global__ __launch_bounds__(BLOCK) void diff_partial(
    const float* __restrict__ pos, const float* __restrict__ radius,
    const float* __restrict__ secretion, const float* __restrict__ Dc,
    const float* __restrict__ Kd, const int* __restrict__ active,
    float* __restrict__ partial,   // C x NN x MM
    int ntiles)                    // tiles per chunk (1 when C=64)
{
    __shared__ float4 sj[JT];      // {x,y,z,r^2} of k-th ACTIVE j
    __shared__ float4 ss[JT * 2];  // premult secretion/(4*pi*D_m)
    __shared__ int s_nact;

    const int tid = threadIdx.x;
    const int i = blockIdx.x * BLOCK + tid;
    const int j0base = blockIdx.y * (JT * ntiles);

    float na[MM], invD[MM], acc[MM];
#pragma unroll
    for (int m = 0; m < MM; ++m) {
        float lam = sqrtf(Dc[m] / Kd[m]);   // exact div+sqrt: keeps the
        na[m] = -LOG2E_F / lam;             // dup015/chain bit-equality gates
        invD[m] = 1.0f / (FOUR_PI_F * Dc[m]);
        acc[m] = 0.0f;
    }
    const bool dup015 = (na[0] == na[1]) && (na[0] == na[5]);
    const bool chain =
        dup015 &&
        (fabsf(na[3] - 2.0f * na[2]) <= 4e-6f * fabsf(na[3])) &&
        (fabsf(na[4] - 2.0f * na[3]) <= 4e-6f * fabsf(na[4]));

    const float px = pos[i * 3 + 0];
    const float py = pos[i * 3 + 1];
    const float pz = pos[i * 3 + 2];

    for (int t = 0; t < ntiles; ++t) {
        const int j0 = j0base + t * JT;
        if (t) __syncthreads();  // protect LDS from previous tile's readers

        // Wave 0 (lanes 0..63) stages + compacts: lane tid owns j0+tid.
        if (tid < JT) {
            const int j = j0 + tid;
            const bool act = (active[j] != 0);
            const unsigned long long mask = __ballot(act);
            if (tid == 0) s_nact = __popcll(mask);
            if (act) {
                const int k = __popcll(mask & ((1ull << tid) - 1ull));
                const float r = radius[j];
                sj[k] = make_float4(pos[j * 3 + 0], pos[j * 3 + 1],
                                    pos[j * 3 + 2], r * r);
                const float4 s0 =
                    reinterpret_cast<const float4*>(secretion)[j * 2 + 0];
                const float4 s1 =
                    reinterpret_cast<const float4*>(secretion)[j * 2 + 1];
                ss[k * 2 + 0] = make_float4(s0.x * invD[0], s0.y * invD[1],
                                            s0.z * invD[2], s0.w * invD[3]);
                ss[k * 2 + 1] = make_float4(s1.x * invD[4], s1.y * invD[5],
                                            s1.z * invD[6], s1.w * invD[7]);
            }
        }
        __syncthreads();

        const int nact = s_nact;
        if (chain)       run_tile<2>(nact, sj, ss, px, py, pz, na, acc);
        else if (dup015) run_tile<1>(nact, sj, ss, px, py, pz, na, acc);
        else             run_tile<0>(nact, sj, ss, px, py, pz, na, acc);
    }

    float4* dst = reinterpret_cast<float4*>(
        partial + (size_t)blockIdx.y * NN * MM + (size_t)i * MM);
    dst[0] = make_float4(acc[0], acc[1], acc[2], acc[3]);
    dst[1] = make_float4(acc[4], acc[5], acc[6], acc[7]);
}

// Reduce: 512 blocks. tx = 16 outputs/block, ty = 16 parallel c-slices.
__global__ __launch_bounds__(BLOCK) void diff_reduce(
    const float4* __restrict__ partial, float4* __restrict__ out, int C)
{
    __shared__ float4 red[16][16];
    const int tx = threadIdx.x & 15;
    const int ty = threadIdx.x >> 4;
    const int o = blockIdx.x * 16 + tx;  // 0 .. NN*MM/4-1

    float4 s = make_float4(0.f, 0.f, 0.f, 0.f);
    for (int c = ty; c < C; c += 16) {
        const float4 p = partial[(size_t)c * (NN * MM / 4) + o];
        s.x += p.x; s.y += p.y; s.z += p.z; s.w += p.w;
    }
    red[ty][tx] = s;
    __syncthreads();
#pragma unroll
    for (int h = 8; h >= 1; h >>= 1) {
        if (ty < h) {
            float4 a = red[ty + h][tx];
            red[ty][tx].x += a.x; red[ty][tx].y += a.y;
            red[ty][tx].z += a.z; red[ty][tx].w += a.w;
        }
        __syncthreads();
    }
    if (ty == 0) out[o] = red[0][tx];
}

extern "C" void kernel_launch(void* const* d_in, const int* in_sizes, int n_in,
                              void* d_out, int out_size, void* d_ws, size_t ws_size,
                              hipStream_t stream) {
    const float* pos       = (const float*)d_in[0];
    const float* radius    = (const float*)d_in[1];
    const float* secretion = (const float*)d_in[2];
    const float* Dc        = (const float*)d_in[3];
    const float* Kd        = (const float*)d_in[4];
    const int*   active    = (const int*)d_in[5];
    float* out = (float*)d_out;

    const size_t slice = (size_t)NN * MM * sizeof(float);  // 128 KB

    int C = CC;
    while (C > 4 && (size_t)C * slice > ws_size) C >>= 1;
    const int ntiles = NN / (C * JT);  // 1 at C=64

    float* partial = (float*)d_ws;
    dim3 grid(NN / BLOCK, C);
    diff_partial<<<grid, BLOCK, 0, stream>>>(pos, radius, secretion, Dc, Kd,
                                             active, partial, ntiles);
    diff_reduce<<<(NN * MM / 4) / 16, BLOCK, 0, stream>>>(
        (const float4*)partial, (float4*)out, C);
}